// Round 12
// baseline (111.652 us; speedup 1.0000x reference)
//
#include <hip/hip_runtime.h>
#include <hip/hip_bf16.h>
#include <stdint.h>

using f32x4  = __attribute__((ext_vector_type(4))) float;
using bf16x8 = __attribute__((ext_vector_type(8))) short;

constexpr int BATCH = 4;
constexpr int LQ_   = 256;
constexpr int LK_   = 50000;
constexpr int OUTD  = 256;
constexpr int EIN   = 128;
constexpr int TR    = 16;                      // k-rows per tile
constexpr int NT    = LK_ / TR;                // 3125 (exact)
constexpr int KCH   = 64;                      // k-chunks per batch (grid 256 = 1/CU)

__device__ __forceinline__ uint32_t f2bf(float f) {
  uint32_t u = __builtin_bit_cast(uint32_t, f);
  u = (u + 0x7fffu + ((u >> 16) & 1u)) >> 16;
  return u;
}

// LDS-only barrier: drains this wave's LDS ops, raw s_barrier, no vmcnt drain.
__device__ __forceinline__ void block_sync_lds() {
  asm volatile("s_waitcnt lgkmcnt(0)" ::: "memory");
  __builtin_amdgcn_sched_barrier(0);
  __builtin_amdgcn_s_barrier();
  __builtin_amdgcn_sched_barrier(0);
}

// ---- prep_all: blocks 0-63 -> Gn, 64-95 -> cast Wv, 96 -> zero num/den ----
__global__ __launch_bounds__(256) void prep_all(
    const float* __restrict__ query, const float* __restrict__ Wq,
    const float* __restrict__ bq,    const float* __restrict__ Wk,
    const float* __restrict__ Wv,    ushort* __restrict__ Gn,
    ushort* __restrict__ Wvbf,       float* __restrict__ numden)
{
  const int blk = blockIdx.x, tid = threadIdx.x;
  if (blk >= 64) {
    if (blk < 96) {                       // cast Wv -> bf16 (32 blocks x 2048)
      int base = (blk - 64) * 2048 + tid * 8;
      float4 a = *(const float4*)(Wv + base);
      float4 c = *(const float4*)(Wv + base + 4);
      uint4 pk;
      pk.x = f2bf(a.x) | (f2bf(a.y) << 16);
      pk.y = f2bf(a.z) | (f2bf(a.w) << 16);
      pk.z = f2bf(c.x) | (f2bf(c.y) << 16);
      pk.w = f2bf(c.z) | (f2bf(c.w) << 16);
      *(uint4*)(Wvbf + base) = pk;
    } else {                              // zero the atomic accumulators
      for (int i = tid; i < 2 * BATCH * OUTD; i += 256) numden[i] = 0.f;
    }
    return;
  }
  // ---- Gn[b] = (1/16)*(query[b]@Wq^T + bq)@Wk, 16 q-rows per block -------
  __shared__ float qin[16 * EIN];
  __shared__ float Qr [16 * OUTD];
  const int b = blk >> 4, q0 = (blk & 15) * 16;
  {
    int idx = tid * 8;
    int row = idx >> 7, c = idx & 127;
    const float* p = query + ((size_t)b * LQ_ + q0 + row) * EIN + c;
    float4 a = *(const float4*)p;
    float4 d = *(const float4*)(p + 4);
    float* q = &qin[row * EIN + c];
    q[0]=a.x; q[1]=a.y; q[2]=a.z; q[3]=a.w; q[4]=d.x; q[5]=d.y; q[6]=d.z; q[7]=d.w;
  }
  __syncthreads();

  float acc[16];
  {
    float bias = bq[tid];
#pragma unroll
    for (int i = 0; i < 16; ++i) acc[i] = bias;
  }
  for (int d4 = 0; d4 < EIN / 4; ++d4) {
    f32x4 w4 = *(const f32x4*)(Wq + tid * EIN + d4 * 4);
#pragma unroll
    for (int i = 0; i < 16; ++i) {
      f32x4 q4 = *(const f32x4*)(qin + i * EIN + d4 * 4);
      acc[i] += q4[0]*w4[0] + q4[1]*w4[1] + q4[2]*w4[2] + q4[3]*w4[3];
    }
  }
#pragma unroll
  for (int i = 0; i < 16; ++i) Qr[i * OUTD + tid] = acc[i];
  __syncthreads();

  float acc2[16];
#pragma unroll
  for (int i = 0; i < 16; ++i) acc2[i] = 0.f;
  for (int d4 = 0; d4 < OUTD / 4; ++d4) {
    float w0 = Wk[(d4*4+0) * OUTD + tid];
    float w1 = Wk[(d4*4+1) * OUTD + tid];
    float w2 = Wk[(d4*4+2) * OUTD + tid];
    float w3 = Wk[(d4*4+3) * OUTD + tid];
#pragma unroll
    for (int i = 0; i < 16; ++i) {
      f32x4 q4 = *(const f32x4*)(Qr + i * OUTD + d4 * 4);
      acc2[i] += q4[0]*w0 + q4[1]*w1 + q4[2]*w2 + q4[3]*w3;
    }
  }
  const float norm = 0.0625f;
#pragma unroll
  for (int i = 0; i < 16; ++i)
    Gn[((size_t)b * LQ_ + q0 + i) * OUTD + tid] = (ushort)f2bf(acc2[i] * norm);
}

// ---- main ------------------------------------------------------------------
// R11 structure (passing, best): 256 blocks (1/CU), 1024 thr = 16 waves, wave
// w owns q-rows [w*16,w*16+16), A-frags 64 VGPR in regs, 2x8KB swizzled bf16
// LDS dbuf, one lgkm-only barrier/iter. NEW in R12: TWO staging reg sets ->
// each global load is issued 2 FULL iterations before its writebuf consumes
// it (~8k cyc in flight vs ~1 compute phase before) -> vmcnt stall ~0. Stage
// moved to loop top (safe: buf[(t+1)&1] last read pre-barrier in iter t-1);
// ds_writes hide under the MFMA phase. Loads clamp to LK-1; tail writes land
// in the never-again-read buffer.
__global__ __launch_bounds__(1024, 4) void attn_main(
    const float*  __restrict__ input, const ushort* __restrict__ Gn,
    const ushort* __restrict__ Wvbf,  float* __restrict__ num,
    float* __restrict__ den)
{
  __shared__ ushort in_lds[2 * 4096]; // 2 x 8 KB
  const int idx = blockIdx.x;
  const int b = idx >> 6, kch = idx & (KCH - 1);
  const int t0 = (kch * NT) >> 6, t1 = ((kch + 1) * NT) >> 6;
  const int tid = threadIdx.x, w = tid >> 6, l = tid & 63;
  const int lg = l >> 4, lr = l & 15;     // lane-group (k-features) / row
  const float* src = input + (size_t)b * LK_ * 256;

  // A-frags (16x16x32): q-row = w*16+lr, features ks*32 + lg*8 + [0,8)
  const int arow = w * 16 + lr;
  const ushort* gp = Gn   + ((size_t)b * LQ_ + arow) * 256 + lg * 8;
  const ushort* vp = Wvbf + (size_t)arow * 256 + lg * 8;
  bf16x8 ga[8], wa[8];
#pragma unroll
  for (int k = 0; k < 8; ++k) {
    ga[k] = *(const bf16x8*)(gp + k * 32);
    wa[k] = *(const bf16x8*)(vp + k * 32);
    asm volatile("" : "+v"(ga[k]), "+v"(wa[k]));  // forbid remat/sink
  }

  float numr[4], denr[4];
#pragma unroll
  for (int r = 0; r < 4; ++r) { numr[r] = 0.f; denr[r] = 0.f; }

  // staging: thread = half-granule. g = tid>>1: row = g>>5 (0..15),
  // fbg = g&31 (0..31), h = tid&1 -> f32 cols fbg*8 + h*4 .. +4.
  const int sg = tid >> 1, sh = tid & 1;
  const int srow = sg >> 5, sfbg = sg & 31;
  const float* sbase = src + sfbg * 8 + sh * 4;
  float4 sA, sB;                    // two in-flight staging sets
  auto loadreg = [&](int t, float4& s) {
    int row = t * TR + srow;
    row = row < LK_ ? row : LK_ - 1;   // clamp: prefetch may overrun chunk
    s = *(const float4*)(sbase + (size_t)row * 256);
  };
  auto writebuf = [&](int buf, const float4& s) {
    char* base = (char*)in_lds + buf * 8192;
    uint2 pk;
    pk.x = f2bf(s.x) | (f2bf(s.y) << 16);
    pk.y = f2bf(s.z) | (f2bf(s.w) << 16);
    *(uint2*)(base + sfbg * 256 + ((srow ^ (sfbg & 15)) << 4) + sh * 8) = pk;
  };

  loadreg(t0, sA);
  writebuf(t0 & 1, sA);
  loadreg(t0 + 1, sB);              // consumed in iter t0
  loadreg(t0 + 2, sA);              // consumed in iter t0+1 (2 iters deep)
  block_sync_lds();

  for (int t = t0; t < t1; ++t) {
    // ---- stage first: write tile t+1 (loaded 2 iters ago), issue t+3 ----
    if ((t - t0) & 1) { writebuf((t + 1) & 1, sA); loadreg(t + 3, sA); }
    else              { writebuf((t + 1) & 1, sB); loadreg(t + 3, sB); }

    // ---- compute(t) from buf[t&1] ----
    const char* bbuf = (const char*)in_lds + (t & 1) * 8192;
    f32x4 aS = {0,0,0,0};
    f32x4 aV = {0,0,0,0};
#pragma unroll
    for (int ks = 0; ks < 8; ++ks) {
      const int fb = ks * 4 + lg;
      bf16x8 bb = *(const bf16x8*)(bbuf + fb * 256 + ((lr ^ (fb & 15)) << 4));
      aS = __builtin_amdgcn_mfma_f32_16x16x32_bf16(ga[ks], bb, aS, 0, 0, 0);
      aV = __builtin_amdgcn_mfma_f32_16x16x32_bf16(wa[ks], bb, aV, 0, 0, 0);
    }
#pragma unroll
    for (int r = 0; r < 4; ++r) {
      float e = __expf(aS[r]);      // no mask: 16 | LK exactly
      denr[r] += e;
      numr[r] += e * aV[r];
    }
    block_sync_lds();               // single lgkm-only barrier per iter
  }

  // reduce over the 16 k-columns (lanes lr), one atomic per (q, {num,den})
#pragma unroll
  for (int r = 0; r < 4; ++r) {
    float d_ = denr[r], n_ = numr[r];
#pragma unroll
    for (int m = 1; m < 16; m <<= 1) {
      d_ += __shfl_xor(d_, m, 64);
      n_ += __shfl_xor(n_, m, 64);
    }
    if (lr == 0) {
      int q = w * 16 + lg * 4 + r;  // D row = (lane>>4)*4 + reg
      atomicAdd(&den[b * OUTD + q], d_);
      atomicAdd(&num[b * OUTD + q], n_);
    }
  }
}

// ---- finalize: out = num/den + bv ------------------------------------------
__global__ __launch_bounds__(256) void finalize(const float* __restrict__ num,
                                                const float* __restrict__ den,
                                                const float* __restrict__ bv,
                                                float* __restrict__ out) {
  int i = blockIdx.x * 256 + threadIdx.x;
  out[i] = num[i] / den[i] + bv[i & 255];
}

extern "C" void kernel_launch(void* const* d_in, const int* in_sizes, int n_in,
                              void* d_out, int out_size, void* d_ws, size_t ws_size,
                              hipStream_t stream)
{
  const float* query = (const float*)d_in[0];
  const float* input = (const float*)d_in[1];
  const float* Wq    = (const float*)d_in[2];
  const float* bq    = (const float*)d_in[3];
  const float* Wk    = (const float*)d_in[4];
  // d_in[5] = bk : softmax-invariant, unused
  const float* Wv    = (const float*)d_in[6];
  const float* bv    = (const float*)d_in[7];
  float* out = (float*)d_out;

  char* ws = (char*)d_ws;
  ushort* Gn     = (ushort*)ws;                       // 512 KB
  ushort* Wvbf   = (ushort*)(ws + 524288);            // 128 KB
  float*  numden = (float*)(ws + 524288 + 131072);    // 8 KB
  float*  num    = numden;
  float*  den    = numden + BATCH * OUTD;

  prep_all<<<97, 256, 0, stream>>>(query, Wq, bq, Wk, Wv, Gn, Wvbf, numden);
  attn_main<<<BATCH * KCH, 1024, 0, stream>>>(input, Gn, Wvbf, num, den);
  finalize<<<BATCH, 256, 0, stream>>>(num, den, bv, out);
}

// Round 13
// 109.381 us; speedup vs baseline: 1.0208x; 1.0208x over previous
//
#include <hip/hip_runtime.h>
#include <hip/hip_bf16.h>
#include <stdint.h>

using f32x4  = __attribute__((ext_vector_type(4))) float;
using bf16x8 = __attribute__((ext_vector_type(8))) short;

constexpr int BATCH = 4;
constexpr int LQ_   = 256;
constexpr int LK_   = 50000;
constexpr int OUTD  = 256;
constexpr int EIN   = 128;
constexpr int TR    = 16;                      // k-rows per tile
constexpr int NT    = LK_ / TR;                // 3125 (exact)
constexpr int KCH   = 64;                      // k-chunks per (b, qb)

__device__ __forceinline__ uint32_t f2bf(float f) {
  uint32_t u = __builtin_bit_cast(uint32_t, f);
  u = (u + 0x7fffu + ((u >> 16) & 1u)) >> 16;
  return u;
}
// packed f32x2 -> bf16x2 (RNE), single instruction
__device__ __forceinline__ uint32_t cvtpk(float lo, float hi) {
  uint32_t r;
  asm volatile("v_cvt_pk_bf16_f32 %0, %1, %2" : "=v"(r) : "v"(lo), "v"(hi));
  return r;
}

// LDS-only barrier: drains this wave's LDS ops, raw s_barrier, no vmcnt drain.
__device__ __forceinline__ void block_sync_lds() {
  asm volatile("s_waitcnt lgkmcnt(0)" ::: "memory");
  __builtin_amdgcn_sched_barrier(0);
  __builtin_amdgcn_s_barrier();
  __builtin_amdgcn_sched_barrier(0);
}

// ---- prep_all: blocks 0-63 -> Gn, 64-95 -> cast Wv, 96 -> zero num/den ----
__global__ __launch_bounds__(256) void prep_all(
    const float* __restrict__ query, const float* __restrict__ Wq,
    const float* __restrict__ bq,    const float* __restrict__ Wk,
    const float* __restrict__ Wv,    ushort* __restrict__ Gn,
    ushort* __restrict__ Wvbf,       float* __restrict__ numden)
{
  const int blk = blockIdx.x, tid = threadIdx.x;
  if (blk >= 64) {
    if (blk < 96) {                       // cast Wv -> bf16 (32 blocks x 2048)
      int base = (blk - 64) * 2048 + tid * 8;
      float4 a = *(const float4*)(Wv + base);
      float4 c = *(const float4*)(Wv + base + 4);
      uint4 pk;
      pk.x = f2bf(a.x) | (f2bf(a.y) << 16);
      pk.y = f2bf(a.z) | (f2bf(a.w) << 16);
      pk.z = f2bf(c.x) | (f2bf(c.y) << 16);
      pk.w = f2bf(c.z) | (f2bf(c.w) << 16);
      *(uint4*)(Wvbf + base) = pk;
    } else {                              // zero the atomic accumulators
      for (int i = tid; i < 2 * BATCH * OUTD; i += 256) numden[i] = 0.f;
    }
    return;
  }
  // ---- Gn[b] = (1/16)*(query[b]@Wq^T + bq)@Wk, 16 q-rows per block -------
  __shared__ float qin[16 * EIN];
  __shared__ float Qr [16 * OUTD];
  const int b = blk >> 4, q0 = (blk & 15) * 16;
  {
    int idx = tid * 8;
    int row = idx >> 7, c = idx & 127;
    const float* p = query + ((size_t)b * LQ_ + q0 + row) * EIN + c;
    float4 a = *(const float4*)p;
    float4 d = *(const float4*)(p + 4);
    float* q = &qin[row * EIN + c];
    q[0]=a.x; q[1]=a.y; q[2]=a.z; q[3]=a.w; q[4]=d.x; q[5]=d.y; q[6]=d.z; q[7]=d.w;
  }
  __syncthreads();

  float acc[16];
  {
    float bias = bq[tid];
#pragma unroll
    for (int i = 0; i < 16; ++i) acc[i] = bias;
  }
  for (int d4 = 0; d4 < EIN / 4; ++d4) {
    f32x4 w4 = *(const f32x4*)(Wq + tid * EIN + d4 * 4);
#pragma unroll
    for (int i = 0; i < 16; ++i) {
      f32x4 q4 = *(const f32x4*)(qin + i * EIN + d4 * 4);
      acc[i] += q4[0]*w4[0] + q4[1]*w4[1] + q4[2]*w4[2] + q4[3]*w4[3];
    }
  }
#pragma unroll
  for (int i = 0; i < 16; ++i) Qr[i * OUTD + tid] = acc[i];
  __syncthreads();

  float acc2[16];
#pragma unroll
  for (int i = 0; i < 16; ++i) acc2[i] = 0.f;
  for (int d4 = 0; d4 < OUTD / 4; ++d4) {
    float w0 = Wk[(d4*4+0) * OUTD + tid];
    float w1 = Wk[(d4*4+1) * OUTD + tid];
    float w2 = Wk[(d4*4+2) * OUTD + tid];
    float w3 = Wk[(d4*4+3) * OUTD + tid];
#pragma unroll
    for (int i = 0; i < 16; ++i) {
      f32x4 q4 = *(const f32x4*)(Qr + i * OUTD + d4 * 4);
      acc2[i] += q4[0]*w0 + q4[1]*w1 + q4[2]*w2 + q4[3]*w3;
    }
  }
  const float norm = 0.0625f;
#pragma unroll
  for (int i = 0; i < 16; ++i)
    Gn[((size_t)b * LQ_ + q0 + i) * OUTD + tid] = (ushort)f2bf(acc2[i] * norm);
}

// ---- main ------------------------------------------------------------------
// 512 blocks (2/CU), 512 thr = 8 waves; block = (b, q-half qb, k-chunk).
// Wave w owns q-rows qb*128 + [w*16, w*16+16) -> the 8 waves cover the block's
// 128-q half. Two blocks/CU = TWO INDEPENDENT BARRIER DOMAINS (R11 had one:
// all 16 waves stalled in lockstep each tile; R13's theory is that this
// lockstep is the residual). qb-pair blocks (idx +/-64, same XCD) read the
// same input tiles ~concurrently -> L2/L3 absorb the 2x logical read (R7:
// FETCH stayed ~103 MB under this pattern). A-frags 64 VGPR, total ~108 <
// 128 cap (512,4) -> 4 waves/SIMD, no demotion pressure. LDS 2x8KB swizzled
// bf16 dbuf; staging = 1 granule/thread (2x dwordx4, contiguous 2KB/wave),
// cvt via v_cvt_pk_bf16_f32 (4 instr vs ~24 manual). R11 cadence: compute ->
// stage(t+1)+issue(t+2) -> single lgkm-only barrier.
__global__ __launch_bounds__(512, 4) void attn_main(
    const float*  __restrict__ input, const ushort* __restrict__ Gn,
    const ushort* __restrict__ Wvbf,  float* __restrict__ num,
    float* __restrict__ den)
{
  __shared__ ushort in_lds[2 * 4096]; // 2 x 8 KB
  const int idx = blockIdx.x;
  const int b = idx >> 7, qb = (idx >> 6) & 1, kch = idx & (KCH - 1);
  const int t0 = (kch * NT) >> 6, t1 = ((kch + 1) * NT) >> 6;
  const int tid = threadIdx.x, w = tid >> 6, l = tid & 63;
  const int lg = l >> 4, lr = l & 15;     // lane-group (k-features) / row
  const float* src = input + (size_t)b * LK_ * 256;

  // A-frags (16x16x32): q-row = qb*128 + w*16 + lr, feats ks*32 + lg*8 + [0,8)
  const int arow = qb * 128 + w * 16 + lr;
  const ushort* gp = Gn   + ((size_t)b * LQ_ + arow) * 256 + lg * 8;
  const ushort* vp = Wvbf + (size_t)arow * 256 + lg * 8;
  bf16x8 ga[8], wa[8];
#pragma unroll
  for (int k = 0; k < 8; ++k) {
    ga[k] = *(const bf16x8*)(gp + k * 32);
    wa[k] = *(const bf16x8*)(vp + k * 32);
    asm volatile("" : "+v"(ga[k]), "+v"(wa[k]));  // forbid remat/sink
  }

  float numr[4], denr[4];
#pragma unroll
  for (int r = 0; r < 4; ++r) { numr[r] = 0.f; denr[r] = 0.f; }

  // staging: thread = one 16B-bf16 granule (8 f32): row = tid>>5 (0..15),
  // fbg = tid&31. Wave loads 2 contiguous rows (2 KB) -> perfect coalescing.
  const int srow = tid >> 5, sfbg = tid & 31;
  const float* sbase = src + sfbg * 8;
  float4 s0, s1;
  auto loadreg = [&](int t) {
    int row = t * TR + srow;
    row = row < LK_ ? row : LK_ - 1;   // clamp: prefetch may overrun chunk
    const float* p = sbase + (size_t)row * 256;
    s0 = *(const float4*)p;
    s1 = *(const float4*)(p + 4);
  };
  auto writebuf = [&](int buf) {
    char* base = (char*)in_lds + buf * 8192;
    uint4 pk;
    pk.x = cvtpk(s0.x, s0.y);
    pk.y = cvtpk(s0.z, s0.w);
    pk.z = cvtpk(s1.x, s1.y);
    pk.w = cvtpk(s1.z, s1.w);
    *(uint4*)(base + sfbg * 256 + ((srow ^ (sfbg & 15)) << 4)) = pk;
  };

  loadreg(t0);
  writebuf(t0 & 1);
  loadreg(t0 + 1);                  // in flight across the barrier
  block_sync_lds();

  for (int t = t0; t < t1; ++t) {
    // ---- compute(t) from buf[t&1] ----
    const char* bbuf = (const char*)in_lds + (t & 1) * 8192;
    f32x4 aS = {0,0,0,0};
    f32x4 aV = {0,0,0,0};
#pragma unroll
    for (int ks = 0; ks < 8; ++ks) {
      const int fb = ks * 4 + lg;
      bf16x8 bb = *(const bf16x8*)(bbuf + fb * 256 + ((lr ^ (fb & 15)) << 4));
      aS = __builtin_amdgcn_mfma_f32_16x16x32_bf16(ga[ks], bb, aS, 0, 0, 0);
      aV = __builtin_amdgcn_mfma_f32_16x16x32_bf16(wa[ks], bb, aV, 0, 0, 0);
    }
#pragma unroll
    for (int r = 0; r < 4; ++r) {
      float e = __expf(aS[r]);      // no mask: 16 | LK exactly
      denr[r] += e;
      numr[r] += e * aV[r];
    }
    // ---- stage: regs(t+1) -> buf[(t+1)&1]; issue loads(t+2) ----
    if (t + 1 < t1) {
      writebuf((t + 1) & 1);        // vmcnt-dep only on loads issued last iter
      if (t + 2 < t1) loadreg(t + 2);
    }
    block_sync_lds();               // single lgkm-only barrier per iter
  }

  // reduce over the 16 k-columns (lanes lr), one atomic per (q, {num,den})
#pragma unroll
  for (int r = 0; r < 4; ++r) {
    float d_ = denr[r], n_ = numr[r];
#pragma unroll
    for (int m = 1; m < 16; m <<= 1) {
      d_ += __shfl_xor(d_, m, 64);
      n_ += __shfl_xor(n_, m, 64);
    }
    if (lr == 0) {
      int q = qb * 128 + w * 16 + lg * 4 + r;   // D row = (lane>>4)*4 + reg
      atomicAdd(&den[b * OUTD + q], d_);
      atomicAdd(&num[b * OUTD + q], n_);
    }
  }
}

// ---- finalize: out = num/den + bv ------------------------------------------
__global__ __launch_bounds__(256) void finalize(const float* __restrict__ num,
                                                const float* __restrict__ den,
                                                const float* __restrict__ bv,
                                                float* __restrict__ out) {
  int i = blockIdx.x * 256 + threadIdx.x;
  out[i] = num[i] / den[i] + bv[i & 255];
}

extern "C" void kernel_launch(void* const* d_in, const int* in_sizes, int n_in,
                              void* d_out, int out_size, void* d_ws, size_t ws_size,
                              hipStream_t stream)
{
  const float* query = (const float*)d_in[0];
  const float* input = (const float*)d_in[1];
  const float* Wq    = (const float*)d_in[2];
  const float* bq    = (const float*)d_in[3];
  const float* Wk    = (const float*)d_in[4];
  // d_in[5] = bk : softmax-invariant, unused
  const float* Wv    = (const float*)d_in[6];
  const float* bv    = (const float*)d_in[7];
  float* out = (float*)d_out;

  char* ws = (char*)d_ws;
  ushort* Gn     = (ushort*)ws;                       // 512 KB
  ushort* Wvbf   = (ushort*)(ws + 524288);            // 128 KB
  float*  numden = (float*)(ws + 524288 + 131072);    // 8 KB
  float*  num    = numden;
  float*  den    = numden + BATCH * OUTD;

  prep_all<<<97, 256, 0, stream>>>(query, Wq, bq, Wk, Wv, Gn, Wvbf, numden);
  attn_main<<<BATCH * 2 * KCH, 512, 0, stream>>>(input, Gn, Wvbf, num, den);
  finalize<<<BATCH, 256, 0, stream>>>(num, den, bv, out);
}

// Round 14
// 107.878 us; speedup vs baseline: 1.0350x; 1.0139x over previous
//
#include <hip/hip_runtime.h>
#include <hip/hip_bf16.h>
#include <stdint.h>

using f32x4  = __attribute__((ext_vector_type(4))) float;
using bf16x8 = __attribute__((ext_vector_type(8))) short;

constexpr int BATCH = 4;
constexpr int LQ_   = 256;
constexpr int LK_   = 50000;
constexpr int OUTD  = 256;
constexpr int EIN   = 128;
constexpr int TR    = 32;                      // k-rows per tile
constexpr int NT    = LK_ / TR;                // 1562.5 -> handled via row clamp
constexpr int NTC   = (LK_ + TR - 1) / TR;     // 1563
constexpr int KCH   = 64;                      // k-chunks per batch (grid 256 = 1/CU)

__device__ __forceinline__ uint32_t f2bf(float f) {
  uint32_t u = __builtin_bit_cast(uint32_t, f);
  u = (u + 0x7fffu + ((u >> 16) & 1u)) >> 16;
  return u;
}
__device__ __forceinline__ uint32_t cvtpk(float lo, float hi) {
  uint32_t r;
  asm volatile("v_cvt_pk_bf16_f32 %0, %1, %2" : "=v"(r) : "v"(lo), "v"(hi));
  return r;
}

// LDS-only barrier: drains this wave's LDS ops, raw s_barrier, no vmcnt drain.
__device__ __forceinline__ void block_sync_lds() {
  asm volatile("s_waitcnt lgkmcnt(0)" ::: "memory");
  __builtin_amdgcn_sched_barrier(0);
  __builtin_amdgcn_s_barrier();
  __builtin_amdgcn_sched_barrier(0);
}

// ---- prep_all: blocks 0-63 -> Gn, 64-95 -> cast Wv, 96 -> zero num/den ----
__global__ __launch_bounds__(256) void prep_all(
    const float* __restrict__ query, const float* __restrict__ Wq,
    const float* __restrict__ bq,    const float* __restrict__ Wk,
    const float* __restrict__ Wv,    ushort* __restrict__ Gn,
    ushort* __restrict__ Wvbf,       float* __restrict__ numden)
{
  const int blk = blockIdx.x, tid = threadIdx.x;
  if (blk >= 64) {
    if (blk < 96) {                       // cast Wv -> bf16 (32 blocks x 2048)
      int base = (blk - 64) * 2048 + tid * 8;
      float4 a = *(const float4*)(Wv + base);
      float4 c = *(const float4*)(Wv + base + 4);
      uint4 pk;
      pk.x = f2bf(a.x) | (f2bf(a.y) << 16);
      pk.y = f2bf(a.z) | (f2bf(a.w) << 16);
      pk.z = f2bf(c.x) | (f2bf(c.y) << 16);
      pk.w = f2bf(c.z) | (f2bf(c.w) << 16);
      *(uint4*)(Wvbf + base) = pk;
    } else {                              // zero the atomic accumulators
      for (int i = tid; i < 2 * BATCH * OUTD; i += 256) numden[i] = 0.f;
    }
    return;
  }
  // ---- Gn[b] = (1/16)*(query[b]@Wq^T + bq)@Wk, 16 q-rows per block -------
  __shared__ float qin[16 * EIN];
  __shared__ float Qr [16 * OUTD];
  const int b = blk >> 4, q0 = (blk & 15) * 16;
  {
    int idx = tid * 8;
    int row = idx >> 7, c = idx & 127;
    const float* p = query + ((size_t)b * LQ_ + q0 + row) * EIN + c;
    float4 a = *(const float4*)p;
    float4 d = *(const float4*)(p + 4);
    float* q = &qin[row * EIN + c];
    q[0]=a.x; q[1]=a.y; q[2]=a.z; q[3]=a.w; q[4]=d.x; q[5]=d.y; q[6]=d.z; q[7]=d.w;
  }
  __syncthreads();

  float acc[16];
  {
    float bias = bq[tid];
#pragma unroll
    for (int i = 0; i < 16; ++i) acc[i] = bias;
  }
  for (int d4 = 0; d4 < EIN / 4; ++d4) {
    f32x4 w4 = *(const f32x4*)(Wq + tid * EIN + d4 * 4);
#pragma unroll
    for (int i = 0; i < 16; ++i) {
      f32x4 q4 = *(const f32x4*)(qin + i * EIN + d4 * 4);
      acc[i] += q4[0]*w4[0] + q4[1]*w4[1] + q4[2]*w4[2] + q4[3]*w4[3];
    }
  }
#pragma unroll
  for (int i = 0; i < 16; ++i) Qr[i * OUTD + tid] = acc[i];
  __syncthreads();

  float acc2[16];
#pragma unroll
  for (int i = 0; i < 16; ++i) acc2[i] = 0.f;
  for (int d4 = 0; d4 < OUTD / 4; ++d4) {
    float w0 = Wk[(d4*4+0) * OUTD + tid];
    float w1 = Wk[(d4*4+1) * OUTD + tid];
    float w2 = Wk[(d4*4+2) * OUTD + tid];
    float w3 = Wk[(d4*4+3) * OUTD + tid];
#pragma unroll
    for (int i = 0; i < 16; ++i) {
      f32x4 q4 = *(const f32x4*)(Qr + i * OUTD + d4 * 4);
      acc2[i] += q4[0]*w0 + q4[1]*w1 + q4[2]*w2 + q4[3]*w3;
    }
  }
  const float norm = 0.0625f;
#pragma unroll
  for (int i = 0; i < 16; ++i)
    Gn[((size_t)b * LQ_ + q0 + i) * OUTD + tid] = (ushort)f2bf(acc2[i] * norm);
}

// ---- main ------------------------------------------------------------------
// R11 base (best: 256 blocks = 1/CU, 1024 thr = 16 waves, 16q/wave, 64-VGPR
// pinned A-frags, swizzled bf16 LDS, lgkm-only barrier) with TR 16->32:
// HALF the barrier/drain/burst-requeue events per k-row, 2x scheduling window
// (16 ds_read + 32 MFMA per iteration). B-read pointers hoisted: per ks one
// pointer; nt=0/1 differ by +-256 B additive (bit4 of row enters the XOR only
// via fb, and lr<16) -> compiler folds into ds_read offset immediates.
// LDS tile: granule (fb 0..31, row 0..31) at fb*512 + ((row^fb)<<4).
// Reads: 16 lanes (lr) within an nt-half span a 16-row XOR-permuted range ->
// 2-way bank aliasing (free). Writes: same family as R11/R13 (measured 0).
__global__ __launch_bounds__(1024, 4) void attn_main(
    const float*  __restrict__ input, const ushort* __restrict__ Gn,
    const ushort* __restrict__ Wvbf,  float* __restrict__ num,
    float* __restrict__ den)
{
  __shared__ ushort in_lds[2 * 8192]; // 2 x 16 KB
  const int idx = blockIdx.x;
  const int b = idx >> 6, kch = idx & (KCH - 1);
  const int t0 = (kch * NTC) >> 6, t1 = ((kch + 1) * NTC) >> 6;
  const int tid = threadIdx.x, w = tid >> 6, l = tid & 63;
  const int lg = l >> 4, lr = l & 15;     // lane-group (features) / lane-row
  const float* src = input + (size_t)b * LK_ * 256;

  // A-frags (16x16x32): q-row = w*16+lr, features ks*32 + lg*8 + [0,8)
  const int arow = w * 16 + lr;
  const ushort* gp = Gn   + ((size_t)b * LQ_ + arow) * 256 + lg * 8;
  const ushort* vp = Wvbf + (size_t)arow * 256 + lg * 8;
  bf16x8 ga[8], wa[8];
#pragma unroll
  for (int k = 0; k < 8; ++k) {
    ga[k] = *(const bf16x8*)(gp + k * 32);
    wa[k] = *(const bf16x8*)(vp + k * 32);
    asm volatile("" : "+v"(ga[k]), "+v"(wa[k]));  // forbid remat/sink
  }

  float numr[4], denr[4];
#pragma unroll
  for (int r = 0; r < 4; ++r) { numr[r] = 0.f; denr[r] = 0.f; }

  // hoisted B-read pointers: ks -> fb = ks*4+lg; base row-slot = lr^fb (nt=0).
  // nt=1 row = lr+16: (lr+16)^fb = (lr^fb)^16 -> byte ^ 256: fb<16 => +256,
  // fb>=16 => -256. Store base = min-byte variant; offsets resolved below.
  const char* rp[8];
#pragma unroll
  for (int ks = 0; ks < 8; ++ks) {
    const int fb = ks * 4 + lg;
    const int slot0 = lr ^ fb;                  // nt=0 slot
    const int slotmin = slot0 & ~16;            // lower of the nt pair
    rp[ks] = (const char*)in_lds + fb * 512 + (slotmin << 4);
  }
  const int hi16 = ((lg >= 4) ? 1 : 0);         // unused placeholder (lg<4 always)
  (void)hi16;
  // whether nt=0 is the +256 variant depends on fb bit4 (= ks>=4)
  // ks<4: nt0 at +0, nt1 at +256 ; ks>=4: nt0 at +256, nt1 at +0

  // staging: thread = one granule: row = tid>>5 (0..31), fb = tid&31.
  const int srow = tid >> 5, sfbg = tid & 31;
  const float* sbase = src + sfbg * 8;
  float4 s0, s1;
  auto loadreg = [&](int t) {
    int row = t * TR + srow;
    row = row < LK_ ? row : LK_ - 1;   // clamp (tail tile + prefetch overrun)
    const float* p = sbase + (size_t)row * 256;
    s0 = *(const float4*)p;
    s1 = *(const float4*)(p + 4);
  };
  const int swoff = sfbg * 512 + ((srow ^ sfbg) << 4);
  auto writebuf = [&](int buf) {
    char* base = (char*)in_lds + buf * 16384;
    uint4 pk;
    pk.x = cvtpk(s0.x, s0.y);
    pk.y = cvtpk(s0.z, s0.w);
    pk.z = cvtpk(s1.x, s1.y);
    pk.w = cvtpk(s1.z, s1.w);
    *(uint4*)(base + swoff) = pk;
  };

  loadreg(t0);
  writebuf(t0 & 1);
  loadreg(t0 + 1);                  // in flight across the barrier
  block_sync_lds();

  const bool tail = (t1 == NTC);    // last chunk holds the 50000-row edge
  for (int t = t0; t < t1; ++t) {
    // ---- compute(t) from buf[t&1]: 2 N-subtiles x 8 ks ----
    const int bufoff = (t & 1) * 16384;
#pragma unroll
    for (int nt = 0; nt < 2; ++nt) {
      f32x4 aS = {0,0,0,0};
      f32x4 aV = {0,0,0,0};
#pragma unroll
      for (int ks = 0; ks < 8; ++ks) {
        // offset: base + buf + (nt==hi-slot ? 256 : 0), all compile-time folds
        const int off = bufoff + (((ks < 4) ? nt : 1 - nt) << 8);
        bf16x8 bb = *(const bf16x8*)(rp[ks] + off);
        aS = __builtin_amdgcn_mfma_f32_16x16x32_bf16(ga[ks], bb, aS, 0, 0, 0);
        aV = __builtin_amdgcn_mfma_f32_16x16x32_bf16(wa[ks], bb, aV, 0, 0, 0);
      }
      const bool valid = !tail || (t * TR + nt * 16 + lr) < LK_;
#pragma unroll
      for (int r = 0; r < 4; ++r) {
        float e = valid ? __expf(aS[r]) : 0.f;
        denr[r] += e;
        numr[r] += e * aV[r];
      }
    }
    // ---- stage: regs(t+1) -> buf[(t+1)&1]; issue loads(t+2) ----
    if (t + 1 < t1) {
      writebuf((t + 1) & 1);        // vmcnt-dep only on loads issued last iter
      if (t + 2 < t1) loadreg(t + 2);
    }
    block_sync_lds();               // single lgkm-only barrier per iter
  }

  // reduce over the 16 k-columns (lanes lr), one atomic per (q, {num,den})
#pragma unroll
  for (int r = 0; r < 4; ++r) {
    float d_ = denr[r], n_ = numr[r];
#pragma unroll
    for (int m = 1; m < 16; m <<= 1) {
      d_ += __shfl_xor(d_, m, 64);
      n_ += __shfl_xor(n_, m, 64);
    }
    if (lr == 0) {
      int q = w * 16 + lg * 4 + r;  // D row = (lane>>4)*4 + reg
      atomicAdd(&den[b * OUTD + q], d_);
      atomicAdd(&num[b * OUTD + q], n_);
    }
  }
}

// ---- finalize: out = num/den + bv ------------------------------------------
__global__ __launch_bounds__(256) void finalize(const float* __restrict__ num,
                                                const float* __restrict__ den,
                                                const float* __restrict__ bv,
                                                float* __restrict__ out) {
  int i = blockIdx.x * 256 + threadIdx.x;
  out[i] = num[i] / den[i] + bv[i & 255];
}

extern "C" void kernel_launch(void* const* d_in, const int* in_sizes, int n_in,
                              void* d_out, int out_size, void* d_ws, size_t ws_size,
                              hipStream_t stream)
{
  const float* query = (const float*)d_in[0];
  const float* input = (const float*)d_in[1];
  const float* Wq    = (const float*)d_in[2];
  const float* bq    = (const float*)d_in[3];
  const float* Wk    = (const float*)d_in[4];
  // d_in[5] = bk : softmax-invariant, unused
  const float* Wv    = (const float*)d_in[6];
  const float* bv    = (const float*)d_in[7];
  float* out = (float*)d_out;

  char* ws = (char*)d_ws;
  ushort* Gn     = (ushort*)ws;                       // 512 KB
  ushort* Wvbf   = (ushort*)(ws + 524288);            // 128 KB
  float*  numden = (float*)(ws + 524288 + 131072);    // 8 KB
  float*  num    = numden;
  float*  den    = numden + BATCH * OUTD;

  prep_all<<<97, 256, 0, stream>>>(query, Wq, bq, Wk, Wv, Gn, Wvbf, numden);
  attn_main<<<BATCH * KCH, 1024, 0, stream>>>(input, Gn, Wvbf, num, den);
  finalize<<<BATCH, 256, 0, stream>>>(num, den, bv, out);
}